// Round 6
// baseline (241.694 us; speedup 1.0000x reference)
//
#include <hip/hip_runtime.h>
#include <math.h>

#define HEADS 16
#define DH    64
#define SEQ   2048
#define HID   1024
#define NROW  4096

typedef __attribute__((ext_vector_type(8))) short bf16x8;
typedef __attribute__((ext_vector_type(4))) float f32x4;

#define AS1 __attribute__((address_space(1)))
#define AS3 __attribute__((address_space(3)))

// 0.125 * log2(e): folds softmax scale and exp->exp2 into the Q pack.
#define QSCALE 0.18033688011112042f

__device__ __forceinline__ unsigned short f2bf(float x) {
    unsigned int u = __builtin_bit_cast(unsigned int, x);
    u = (u + 0x7FFFu + ((u >> 16) & 1u)) >> 16;
    return (unsigned short)u;
}

__device__ __forceinline__ void gload_lds16(const unsigned short* g, unsigned short* l) {
    __builtin_amdgcn_global_load_lds((AS1 void*)g, (AS3 void*)l, 16, 0, 0);
}

// ================= prep: conv_x + rope_tab + 2x wtrans in ONE launch =================
__device__ void wtrans_body(const float* __restrict__ wsrc, unsigned short* __restrict__ wt,
                            int K, int N, int bx, int by, float (*T)[65])
{
    const int tid = threadIdx.x;
    const int k0 = by * 64, n0 = bx * 64;
    #pragma unroll
    for (int rnd = 0; rnd < 4; ++rnd) {
        int row = (tid >> 4) + rnd * 16;
        int c = (tid & 15) * 4;
        float4 v = *(const float4*)&wsrc[(size_t)(k0 + row) * N + n0 + c];
        T[row][c] = v.x; T[row][c+1] = v.y; T[row][c+2] = v.z; T[row][c+3] = v.w;
    }
    __syncthreads();
    const int sr = tid >> 3, sc = (tid & 7) << 3;
    #pragma unroll
    for (int half = 0; half < 2; ++half) {
        int n = sr + half * 32;
        union { unsigned short u[8]; bf16x8 v; } pk;
        #pragma unroll
        for (int j = 0; j < 8; ++j) pk.u[j] = f2bf(T[sc + j][n]);
        *(bf16x8*)&wt[(size_t)(n0 + n) * K + k0 + sc] = pk.v;
    }
}

__global__ __launch_bounds__(256) void prep(const float* __restrict__ x,
                                            const float* __restrict__ rot,
                                            const float* __restrict__ w_qkv,
                                            const float* __restrict__ w_out,
                                            unsigned short* __restrict__ xb,
                                            float2* __restrict__ ctab,
                                            unsigned short* __restrict__ wqkvT,
                                            unsigned short* __restrict__ woutT)
{
    __shared__ float T[64][65];
    const int bid = blockIdx.x;
    if (bid < 2048) {
        size_t i = ((size_t)bid * 256 + threadIdx.x) * 8;
        float4 a = *(const float4*)&x[i];
        float4 b = *(const float4*)&x[i + 4];
        union { unsigned short u[8]; bf16x8 v; } pk;
        pk.u[0] = f2bf(a.x); pk.u[1] = f2bf(a.y); pk.u[2] = f2bf(a.z); pk.u[3] = f2bf(a.w);
        pk.u[4] = f2bf(b.x); pk.u[5] = f2bf(b.y); pk.u[6] = f2bf(b.z); pk.u[7] = f2bf(b.w);
        *(bf16x8*)&xb[i] = pk.v;
    } else if (bid < 2560) {
        int i = (bid - 2048) * 256 + threadIdx.x;   // SEQ*DH = 131072
        float r = rot[i];
        float s, c;
        __sincosf(r, &s, &c);
        ctab[i] = make_float2(c, s);
    } else if (bid < 3328) {
        int idx = bid - 2560;                       // 48 x 16
        wtrans_body(w_qkv, wqkvT, 1024, 3072, idx % 48, idx / 48, T);
    } else {
        int idx = bid - 3328;                       // 16 x 16
        wtrans_body(w_out, woutT, 1024, 1024, idx % 16, idx / 16, T);
    }
}

// ========== QKV GEMM, BK=64 (two 32-k LDS regions), fused RoPE/split/V^T epilogue ==========
__global__ __launch_bounds__(256) void gemm_qkv(const unsigned short* __restrict__ A,
                                                const unsigned short* __restrict__ Bt,
                                                const float2* __restrict__ ctab,
                                                unsigned short* __restrict__ qb,
                                                unsigned short* __restrict__ kb,
                                                unsigned short* __restrict__ vt)
{
    __shared__ __align__(16) unsigned short As[2 * 128 * 32];
    __shared__ __align__(16) unsigned short Bs[2 * 128 * 32];
    const int tid = threadIdx.x;
    const int w = tid >> 6, lane = tid & 63;
    const int quad = lane >> 4, lm = lane & 15;
    const int wr = (w >> 1) * 64, wc = (w & 1) * 64;
    const int bm = blockIdx.y * 128, bn = blockIdx.x * 128;
    const int m0 = tid >> 2;               // 0..63
    const int sk = (tid & 3) << 3;         // 0,8,16,24

    f32x4 acc[4][4];
    #pragma unroll
    for (int i = 0; i < 4; ++i)
        #pragma unroll
        for (int j = 0; j < 4; ++j) acc[i][j] = (f32x4){0.f, 0.f, 0.f, 0.f};

    for (int k0 = 0; k0 < 1024; k0 += 64) {
        __syncthreads();
        #pragma unroll
        for (int r = 0; r < 2; ++r) {
            const int kk = k0 + r * 32 + sk;
            gload_lds16(&A [(size_t)(bm + m0     ) * 1024 + kk], As + r * 4096 + (size_t)w * 512);
            gload_lds16(&A [(size_t)(bm + m0 + 64) * 1024 + kk], As + r * 4096 + 2048 + (size_t)w * 512);
            gload_lds16(&Bt[(size_t)(bn + m0     ) * 1024 + kk], Bs + r * 4096 + (size_t)w * 512);
            gload_lds16(&Bt[(size_t)(bn + m0 + 64) * 1024 + kk], Bs + r * 4096 + 2048 + (size_t)w * 512);
        }
        __syncthreads();
        #pragma unroll
        for (int r = 0; r < 2; ++r) {
            bf16x8 af[4], bfr[4];
            #pragma unroll
            for (int mt = 0; mt < 4; ++mt) af[mt] = *(const bf16x8*)&As[r * 4096 + (wr + mt * 16 + lm) * 32 + quad * 8];
            #pragma unroll
            for (int nt = 0; nt < 4; ++nt) bfr[nt] = *(const bf16x8*)&Bs[r * 4096 + (wc + nt * 16 + lm) * 32 + quad * 8];
            #pragma unroll
            for (int mt = 0; mt < 4; ++mt)
                #pragma unroll
                for (int nt = 0; nt < 4; ++nt)
                    acc[mt][nt] = __builtin_amdgcn_mfma_f32_16x16x32_bf16(af[mt], bfr[nt], acc[mt][nt], 0, 0, 0);
        }
    }

    const int colbase = bn + wc;
    const int region = colbase >> 10;      // 0=q, 1=k, 2=v
    const int h = (colbase >> 6) & 15;

    if (region == 2) {
        #pragma unroll
        for (int mt = 0; mt < 4; ++mt) {
            int rowb = bm + wr + mt * 16 + quad * 4;
            int b = rowb >> 11, seq = rowb & (SEQ - 1);
            #pragma unroll
            for (int nt = 0; nt < 4; ++nt) {
                int d = nt * 16 + lm;
                ushort4 pk;
                pk.x = f2bf(acc[mt][nt][0]); pk.y = f2bf(acc[mt][nt][1]);
                pk.z = f2bf(acc[mt][nt][2]); pk.w = f2bf(acc[mt][nt][3]);
                *(ushort4*)&vt[((size_t)(b * HEADS + h) * DH + d) * SEQ + seq] = pk;
            }
        }
    } else {
        const float qs = (region == 0) ? QSCALE : 1.0f;
        unsigned short* dst = (region == 0) ? qb : kb;
        #pragma unroll
        for (int mt = 0; mt < 4; ++mt) {
            #pragma unroll
            for (int nt = 0; nt < 2; ++nt) {
                int d = nt * 16 + lm;
                #pragma unroll
                for (int r = 0; r < 4; ++r) {
                    int row = bm + wr + mt * 16 + quad * 4 + r;
                    int b = row >> 11, seq = row & (SEQ - 1);
                    float2 cs0 = ctab[seq * DH + d];
                    float2 cs1 = ctab[seq * DH + d + 32];
                    float x0 = acc[mt][nt][r];
                    float x1 = acc[mt][nt + 2][r];
                    size_t ob = ((size_t)(b * HEADS + h) * SEQ + seq) * DH;
                    dst[ob + d]      = f2bf((x0 * cs0.x - x1 * cs0.y) * qs);
                    dst[ob + d + 32] = f2bf((x1 * cs1.x + x0 * cs1.y) * qs);
                }
            }
        }
    }
}

// ========== Flash attention v5: attn4 + one-iter-deep register prefetch ==========
// block = 256 thr = 4 waves; wave w = k-group w (kseq [w*512, w*512+512)), all waves
// share the block's 64 q rows. grid (SEQ/64, BSZ*HEADS). Barrier-free k-loop.
#define PSW 36
#define OPW 68
__global__ __launch_bounds__(256) void attn5(const unsigned short* __restrict__ qb,
                                             const unsigned short* __restrict__ kb,
                                             const unsigned short* __restrict__ vt,
                                             unsigned short* __restrict__ attnb)
{
    __shared__ __align__(16) char smem[4 * 64 * PSW * 2];   // 18432 B
    unsigned short* Ps   = (unsigned short*)smem;           // [4 waves][64 q][PSW]
    float*          oBuf = (float*)smem;                    // merge overlay [64][OPW] = 17408 B
    float*          lRed = (float*)(smem + 17408);          // [3][64] = 768 B

    const int tid = threadIdx.x;
    const int w = tid >> 6, lane = tid & 63, quad = lane >> 4, lm = lane & 15;
    const int bh = blockIdx.y, q0 = blockIdx.x * 64;
    const int b = bh >> 4, h = bh & 15;
    const size_t hb = (size_t)bh * SEQ * DH;   // also base for vt [bh][64][2048]
    unsigned short* myPs = Ps + w * (64 * PSW);

    // Q fragments in registers
    bf16x8 qf[4][2];
    #pragma unroll
    for (int qt = 0; qt < 4; ++qt)
        #pragma unroll
        for (int c = 0; c < 2; ++c)
            qf[qt][c] = *(const bf16x8*)&qb[hb + (size_t)(q0 + qt * 16 + lm) * DH + c * 32 + quad * 8];

    float rs[4] = {0.f, 0.f, 0.f, 0.f};
    f32x4 o[4][4];   // [qt][dt]
    #pragma unroll
    for (int qt = 0; qt < 4; ++qt)
        #pragma unroll
        for (int dt = 0; dt < 4; ++dt) o[qt][dt] = (f32x4){0.f, 0.f, 0.f, 0.f};

    const int kstart = w * 512;
    // per-lane base addresses
    const unsigned short* kbase_p = &kb[hb + (size_t)(kstart + lm) * DH + quad * 8];      // + kt*16*DH, +32 for c=1
    const unsigned short* vbase_p = &vt[hb + (size_t)lm * SEQ + kstart + quad * 8];       // + dt*16*SEQ, + kseq offs

    // prime the pipeline: load iter 0 fragments
    bf16x8 kf[2][2], vf[4];
    #pragma unroll
    for (int kt = 0; kt < 2; ++kt)
        #pragma unroll
        for (int c = 0; c < 2; ++c)
            kf[kt][c] = *(const bf16x8*)(kbase_p + (size_t)kt * 16 * DH + c * 32);
    #pragma unroll
    for (int dt = 0; dt < 4; ++dt)
        vf[dt] = *(const bf16x8*)(vbase_p + (size_t)dt * 16 * SEQ);

    for (int it = 0; it < 16; ++it) {
        // prefetch next iteration's fragments ((it+1)&15 wraps -> always in-bounds)
        const int nit = (it + 1) & 15;
        bf16x8 nkf[2][2], nvf[4];
        #pragma unroll
        for (int kt = 0; kt < 2; ++kt)
            #pragma unroll
            for (int c = 0; c < 2; ++c)
                nkf[kt][c] = *(const bf16x8*)(kbase_p + (size_t)(nit * 32 + kt * 16) * DH + c * 32);
        #pragma unroll
        for (int dt = 0; dt < 4; ++dt)
            nvf[dt] = *(const bf16x8*)(vbase_p + (size_t)dt * 16 * SEQ + nit * 32);

        // S^T = K Q^T  (C: col q = lm, row kseq = kt*16 + quad*4 + r)
        #pragma unroll
        for (int kt = 0; kt < 2; ++kt) {
            f32x4 s[4];
            #pragma unroll
            for (int qt = 0; qt < 4; ++qt) {
                f32x4 z = (f32x4){0.f, 0.f, 0.f, 0.f};
                z = __builtin_amdgcn_mfma_f32_16x16x32_bf16(kf[kt][0], qf[qt][0], z, 0, 0, 0);
                s[qt] = __builtin_amdgcn_mfma_f32_16x16x32_bf16(kf[kt][1], qf[qt][1], z, 0, 0, 0);
            }
            #pragma unroll
            for (int qt = 0; qt < 4; ++qt) {
                unsigned int u[4];
                #pragma unroll
                for (int r = 0; r < 4; ++r) {
                    float p = __builtin_amdgcn_exp2f(s[qt][r]);
                    unsigned int pu = __builtin_bit_cast(unsigned int, p) & 0xFFFF0000u;
                    rs[qt] += __builtin_bit_cast(float, pu);
                    u[r] = pu;
                }
                unsigned int lo = __builtin_amdgcn_perm(u[1], u[0], 0x07060302);
                unsigned int hi = __builtin_amdgcn_perm(u[3], u[2], 0x07060302);
                unsigned long long pv = ((unsigned long long)hi << 32) | lo;
                *(unsigned long long*)&myPs[(qt * 16 + lm) * PSW + kt * 16 + quad * 4] = pv;
            }
        }
        // O += P V
        #pragma unroll
        for (int qt = 0; qt < 4; ++qt) {
            bf16x8 pf = *(const bf16x8*)&myPs[(qt * 16 + lm) * PSW + quad * 8];
            #pragma unroll
            for (int dt = 0; dt < 4; ++dt)
                o[qt][dt] = __builtin_amdgcn_mfma_f32_16x16x32_bf16(pf, vf[dt], o[qt][dt], 0, 0, 0);
        }
        // rotate prefetched fragments in
        #pragma unroll
        for (int kt = 0; kt < 2; ++kt)
            #pragma unroll
            for (int c = 0; c < 2; ++c) kf[kt][c] = nkf[kt][c];
        #pragma unroll
        for (int dt = 0; dt < 4; ++dt) vf[dt] = nvf[dt];
    }

    // reduce rs across quads
    #pragma unroll
    for (int off = 16; off < 64; off <<= 1)
        #pragma unroll
        for (int qt = 0; qt < 4; ++qt) rs[qt] += __shfl_xor(rs[qt], off, 64);

    // merge the 4 k-groups
    __syncthreads();
    if (w > 0 && quad == 0) {
        #pragma unroll
        for (int qt = 0; qt < 4; ++qt) lRed[(w - 1) * 64 + qt * 16 + lm] = rs[qt];
    }
    __syncthreads();
    if (w == 0) {
        #pragma unroll
        for (int qt = 0; qt < 4; ++qt)
            rs[qt] += lRed[qt * 16 + lm] + lRed[64 + qt * 16 + lm] + lRed[128 + qt * 16 + lm];
    }
    #pragma unroll
    for (int s = 1; s < 4; ++s) {
        __syncthreads();
        if (w == s) {
            #pragma unroll
            for (int qt = 0; qt < 4; ++qt)
                #pragma unroll
                for (int dt = 0; dt < 4; ++dt)
                    #pragma unroll
                    for (int r = 0; r < 4; ++r)
                        oBuf[(qt * 16 + quad * 4 + r) * OPW + dt * 16 + lm] = o[qt][dt][r];
        }
        __syncthreads();
        if (w == 0) {
            #pragma unroll
            for (int qt = 0; qt < 4; ++qt)
                #pragma unroll
                for (int dt = 0; dt < 4; ++dt)
                    #pragma unroll
                    for (int r = 0; r < 4; ++r)
                        o[qt][dt][r] += oBuf[(qt * 16 + quad * 4 + r) * OPW + dt * 16 + lm];
        }
    }
    if (w == 0) {
        #pragma unroll
        for (int qt = 0; qt < 4; ++qt)
            #pragma unroll
            for (int r = 0; r < 4; ++r) {
                float inv = 1.0f / __shfl(rs[qt], quad * 4 + r, 64);
                int row = b * SEQ + q0 + qt * 16 + quad * 4 + r;
                #pragma unroll
                for (int dt = 0; dt < 4; ++dt)
                    attnb[(size_t)row * HID + h * DH + dt * 16 + lm] = f2bf(o[qt][dt][r] * inv);
            }
    }
}

// ========== output GEMM: 64x128 tiles ==========
__global__ __launch_bounds__(256) void gemm_out(const unsigned short* __restrict__ A,
                                                const unsigned short* __restrict__ Bt,
                                                float* __restrict__ C)
{
    __shared__ __align__(16) unsigned short As[64 * 32];
    __shared__ __align__(16) unsigned short Bs[128 * 32];
    const int tid = threadIdx.x;
    const int w = tid >> 6, lane = tid & 63;
    const int quad = lane >> 4, lm = lane & 15;
    const int wr = (w >> 1) * 32, wc = (w & 1) * 64;
    const int bm = blockIdx.y * 64, bn = blockIdx.x * 128;
    const int m0 = tid >> 2;
    const int sk = (tid & 3) << 3;

    f32x4 acc[2][4];
    #pragma unroll
    for (int i = 0; i < 2; ++i)
        #pragma unroll
        for (int j = 0; j < 4; ++j) acc[i][j] = (f32x4){0.f, 0.f, 0.f, 0.f};

    for (int k0 = 0; k0 < 1024; k0 += 32) {
        __syncthreads();
        gload_lds16(&A [(size_t)(bm + m0     ) * 1024 + k0 + sk], As + (size_t)w * 512);
        gload_lds16(&Bt[(size_t)(bn + m0     ) * 1024 + k0 + sk], Bs + (size_t)w * 512);
        gload_lds16(&Bt[(size_t)(bn + m0 + 64) * 1024 + k0 + sk], Bs + 2048 + (size_t)w * 512);
        __syncthreads();
        bf16x8 af[2], bfr[4];
        #pragma unroll
        for (int mt = 0; mt < 2; ++mt) af[mt] = *(const bf16x8*)&As[(wr + mt * 16 + lm) * 32 + quad * 8];
        #pragma unroll
        for (int nt = 0; nt < 4; ++nt) bfr[nt] = *(const bf16x8*)&Bs[(wc + nt * 16 + lm) * 32 + quad * 8];
        #pragma unroll
        for (int mt = 0; mt < 2; ++mt)
            #pragma unroll
            for (int nt = 0; nt < 4; ++nt)
                acc[mt][nt] = __builtin_amdgcn_mfma_f32_16x16x32_bf16(af[mt], bfr[nt], acc[mt][nt], 0, 0, 0);
    }

    #pragma unroll
    for (int mt = 0; mt < 2; ++mt)
        #pragma unroll
        for (int nt = 0; nt < 4; ++nt) {
            int col = bn + wc + nt * 16 + lm;
            #pragma unroll
            for (int r = 0; r < 4; ++r) {
                int row = bm + wr + mt * 16 + quad * 4 + r;
                C[(size_t)row * 1024 + col] = acc[mt][nt][r];
            }
        }
}

extern "C" void kernel_launch(void* const* d_in, const int* in_sizes, int n_in,
                              void* d_out, int out_size, void* d_ws, size_t ws_size,
                              hipStream_t stream) {
    const float* x     = (const float*)d_in[0];
    const float* rot   = (const float*)d_in[1];
    const float* w_qkv = (const float*)d_in[2];
    const float* w_out = (const float*)d_in[3];
    float* out = (float*)d_out;

    char* ws = (char*)d_ws;
    unsigned short* xb    = (unsigned short*)(ws);                         // 8 MB
    unsigned short* qb    = (unsigned short*)(ws + (size_t)( 8u << 20));   // 8 MB [bh][seq][64]
    unsigned short* kb    = (unsigned short*)(ws + (size_t)(16u << 20));   // 8 MB [bh][seq][64]
    unsigned short* vt    = (unsigned short*)(ws + (size_t)(24u << 20));   // 8 MB [bh][64][seq]
    unsigned short* attnb = (unsigned short*)(ws + (size_t)(32u << 20));   // 8 MB
    unsigned short* wqkvT = (unsigned short*)(ws + (size_t)(40u << 20));   // 6 MB
    unsigned short* woutT = (unsigned short*)(ws + (size_t)(46u << 20));   // 2 MB
    float2*         ctab  = (float2*)        (ws + (size_t)(48u << 20));   // 1 MB

    prep<<<3584, 256, 0, stream>>>(x, rot, w_qkv, w_out, xb, ctab, wqkvT, woutT);

    gemm_qkv<<<dim3(24, 32), 256, 0, stream>>>(xb, wqkvT, ctab, qb, kb, vt);

    attn5<<<dim3(SEQ / 64, 32), 256, 0, stream>>>(qb, kb, vt, attnb);

    gemm_out<<<dim3(8, 64), 256, 0, stream>>>(attnb, woutT, out);
}

// Round 7
// 211.792 us; speedup vs baseline: 1.1412x; 1.1412x over previous
//
#include <hip/hip_runtime.h>
#include <math.h>

#define HEADS 16
#define DH    64
#define SEQ   2048
#define HID   1024
#define NROW  4096

typedef __attribute__((ext_vector_type(8))) short bf16x8;
typedef __attribute__((ext_vector_type(4))) float f32x4;

#define AS1 __attribute__((address_space(1)))
#define AS3 __attribute__((address_space(3)))

// 0.125 * log2(e): folds softmax scale and exp->exp2 into the Q pack.
#define QSCALE 0.18033688011112042f

__device__ __forceinline__ unsigned short f2bf(float x) {
    unsigned int u = __builtin_bit_cast(unsigned int, x);
    u = (u + 0x7FFFu + ((u >> 16) & 1u)) >> 16;
    return (unsigned short)u;
}

__device__ __forceinline__ void gload_lds16(const unsigned short* g, unsigned short* l) {
    __builtin_amdgcn_global_load_lds((AS1 void*)g, (AS3 void*)l, 16, 0, 0);
}

// ================= prep: conv_x + rope_tab + 2x wtrans in ONE launch =================
__device__ void wtrans_body(const float* __restrict__ wsrc, unsigned short* __restrict__ wt,
                            int K, int N, int bx, int by, float (*T)[65])
{
    const int tid = threadIdx.x;
    const int k0 = by * 64, n0 = bx * 64;
    #pragma unroll
    for (int rnd = 0; rnd < 4; ++rnd) {
        int row = (tid >> 4) + rnd * 16;
        int c = (tid & 15) * 4;
        float4 v = *(const float4*)&wsrc[(size_t)(k0 + row) * N + n0 + c];
        T[row][c] = v.x; T[row][c+1] = v.y; T[row][c+2] = v.z; T[row][c+3] = v.w;
    }
    __syncthreads();
    const int sr = tid >> 3, sc = (tid & 7) << 3;
    #pragma unroll
    for (int half = 0; half < 2; ++half) {
        int n = sr + half * 32;
        union { unsigned short u[8]; bf16x8 v; } pk;
        #pragma unroll
        for (int j = 0; j < 8; ++j) pk.u[j] = f2bf(T[sc + j][n]);
        *(bf16x8*)&wt[(size_t)(n0 + n) * K + k0 + sc] = pk.v;
    }
}

__global__ __launch_bounds__(256) void prep(const float* __restrict__ x,
                                            const float* __restrict__ rot,
                                            const float* __restrict__ w_qkv,
                                            const float* __restrict__ w_out,
                                            unsigned short* __restrict__ xb,
                                            float2* __restrict__ ctab,
                                            unsigned short* __restrict__ wqkvT,
                                            unsigned short* __restrict__ woutT)
{
    __shared__ float T[64][65];
    const int bid = blockIdx.x;
    if (bid < 2048) {
        size_t i = ((size_t)bid * 256 + threadIdx.x) * 8;
        float4 a = *(const float4*)&x[i];
        float4 b = *(const float4*)&x[i + 4];
        union { unsigned short u[8]; bf16x8 v; } pk;
        pk.u[0] = f2bf(a.x); pk.u[1] = f2bf(a.y); pk.u[2] = f2bf(a.z); pk.u[3] = f2bf(a.w);
        pk.u[4] = f2bf(b.x); pk.u[5] = f2bf(b.y); pk.u[6] = f2bf(b.z); pk.u[7] = f2bf(b.w);
        *(bf16x8*)&xb[i] = pk.v;
    } else if (bid < 2560) {
        int i = (bid - 2048) * 256 + threadIdx.x;   // SEQ*DH = 131072
        float r = rot[i];
        float s, c;
        __sincosf(r, &s, &c);
        ctab[i] = make_float2(c, s);
    } else if (bid < 3328) {
        int idx = bid - 2560;                       // 48 x 16
        wtrans_body(w_qkv, wqkvT, 1024, 3072, idx % 48, idx / 48, T);
    } else {
        int idx = bid - 3328;                       // 16 x 16
        wtrans_body(w_out, woutT, 1024, 1024, idx % 16, idx / 16, T);
    }
}

// ========== QKV GEMM, BK=32 (R4 structure), fused RoPE/split epilogue ==========
// V written to TILED layout: vt[bh][t=seq/32][d=64][ks=32]
__global__ __launch_bounds__(256) void gemm_qkv(const unsigned short* __restrict__ A,
                                                const unsigned short* __restrict__ Bt,
                                                const float2* __restrict__ ctab,
                                                unsigned short* __restrict__ qb,
                                                unsigned short* __restrict__ kb,
                                                unsigned short* __restrict__ vt)
{
    __shared__ __align__(16) unsigned short As[128 * 32];
    __shared__ __align__(16) unsigned short Bs[128 * 32];
    const int tid = threadIdx.x;
    const int w = tid >> 6, lane = tid & 63;
    const int quad = lane >> 4, lm = lane & 15;
    const int wr = (w >> 1) * 64, wc = (w & 1) * 64;
    const int bm = blockIdx.y * 128, bn = blockIdx.x * 128;
    const int m0 = tid >> 2;
    const int sk = (tid & 3) << 3;

    f32x4 acc[4][4];
    #pragma unroll
    for (int i = 0; i < 4; ++i)
        #pragma unroll
        for (int j = 0; j < 4; ++j) acc[i][j] = (f32x4){0.f, 0.f, 0.f, 0.f};

    for (int k0 = 0; k0 < 1024; k0 += 32) {
        __syncthreads();
        gload_lds16(&A [(size_t)(bm + m0     ) * 1024 + k0 + sk], As + (size_t)w * 512);
        gload_lds16(&A [(size_t)(bm + m0 + 64) * 1024 + k0 + sk], As + 2048 + (size_t)w * 512);
        gload_lds16(&Bt[(size_t)(bn + m0     ) * 1024 + k0 + sk], Bs + (size_t)w * 512);
        gload_lds16(&Bt[(size_t)(bn + m0 + 64) * 1024 + k0 + sk], Bs + 2048 + (size_t)w * 512);
        __syncthreads();
        bf16x8 af[4], bfr[4];
        #pragma unroll
        for (int mt = 0; mt < 4; ++mt) af[mt] = *(const bf16x8*)&As[(wr + mt * 16 + lm) * 32 + quad * 8];
        #pragma unroll
        for (int nt = 0; nt < 4; ++nt) bfr[nt] = *(const bf16x8*)&Bs[(wc + nt * 16 + lm) * 32 + quad * 8];
        #pragma unroll
        for (int mt = 0; mt < 4; ++mt)
            #pragma unroll
            for (int nt = 0; nt < 4; ++nt)
                acc[mt][nt] = __builtin_amdgcn_mfma_f32_16x16x32_bf16(af[mt], bfr[nt], acc[mt][nt], 0, 0, 0);
    }

    const int colbase = bn + wc;
    const int region = colbase >> 10;      // 0=q, 1=k, 2=v
    const int h = (colbase >> 6) & 15;

    if (region == 2) {
        #pragma unroll
        for (int mt = 0; mt < 4; ++mt) {
            int rowb = bm + wr + mt * 16 + quad * 4;
            int b = rowb >> 11, seq = rowb & (SEQ - 1);
            int t = seq >> 5, ks = seq & 31;
            #pragma unroll
            for (int nt = 0; nt < 4; ++nt) {
                int d = nt * 16 + lm;
                ushort4 pk;
                pk.x = f2bf(acc[mt][nt][0]); pk.y = f2bf(acc[mt][nt][1]);
                pk.z = f2bf(acc[mt][nt][2]); pk.w = f2bf(acc[mt][nt][3]);
                *(ushort4*)&vt[(((size_t)(b * HEADS + h) * 64 + t) * 64 + d) * 32 + ks] = pk;
            }
        }
    } else {
        const float qs = (region == 0) ? QSCALE : 1.0f;
        unsigned short* dst = (region == 0) ? qb : kb;
        #pragma unroll
        for (int mt = 0; mt < 4; ++mt) {
            #pragma unroll
            for (int nt = 0; nt < 2; ++nt) {
                int d = nt * 16 + lm;
                #pragma unroll
                for (int r = 0; r < 4; ++r) {
                    int row = bm + wr + mt * 16 + quad * 4 + r;
                    int b = row >> 11, seq = row & (SEQ - 1);
                    float2 cs0 = ctab[seq * DH + d];
                    float2 cs1 = ctab[seq * DH + d + 32];
                    float x0 = acc[mt][nt][r];
                    float x1 = acc[mt][nt + 2][r];
                    size_t ob = ((size_t)(b * HEADS + h) * SEQ + seq) * DH;
                    dst[ob + d]      = f2bf((x0 * cs0.x - x1 * cs0.y) * qs);
                    dst[ob + d + 32] = f2bf((x1 * cs1.x + x0 * cs1.y) * qs);
                }
            }
        }
    }
}

// ========== Flash attention v6: VALU-lean attn4, imm-offset addressing, 3 waves/SIMD ==========
// block = 256 thr = 4 waves; wave w = k-group w (kseq [w*512, w*512+512)); all waves
// share the block's 64 q rows. grid (SEQ/64, BSZ*HEADS). Barrier-free k-loop.
#define PSW 36
#define OPW 68
__global__ __launch_bounds__(256, 3) void attn6(const unsigned short* __restrict__ qb,
                                                const unsigned short* __restrict__ kb,
                                                const unsigned short* __restrict__ vt,
                                                unsigned short* __restrict__ attnb)
{
    __shared__ __align__(16) char smem[4 * 64 * PSW * 2];   // 18432 B
    unsigned short* Ps   = (unsigned short*)smem;           // [4 waves][64 q][PSW]
    float*          oBuf = (float*)smem;                    // merge overlay [64][OPW] = 17408 B
    float*          lRed = (float*)(smem + 17408);          // [3][64] = 768 B

    const int tid = threadIdx.x;
    const int w = tid >> 6, lane = tid & 63, quad = lane >> 4, lm = lane & 15;
    const int bh = blockIdx.y, q0 = blockIdx.x * 64;
    const int b = bh >> 4, h = bh & 15;
    const size_t hb = (size_t)bh * SEQ * DH;
    unsigned short* myPs = Ps + w * (64 * PSW);

    // Q fragments in registers (B-operand: lane q = lm, k = c*32 + quad*8 + j)
    bf16x8 qf[4][2];
    #pragma unroll
    for (int qt = 0; qt < 4; ++qt)
        #pragma unroll
        for (int c = 0; c < 2; ++c)
            qf[qt][c] = *(const bf16x8*)&qb[hb + (size_t)(q0 + qt * 16 + lm) * DH + c * 32 + quad * 8];

    float rs[4] = {0.f, 0.f, 0.f, 0.f};
    f32x4 o[4][4];   // [qt][dt]
    #pragma unroll
    for (int qt = 0; qt < 4; ++qt)
        #pragma unroll
        for (int dt = 0; dt < 4; ++dt) o[qt][dt] = (f32x4){0.f, 0.f, 0.f, 0.f};

    // incremented base pointers; all per-iter variation is immediate offsets
    const unsigned short* kp = kb + hb + (size_t)(w * 512 + lm) * DH + quad * 8;
    const unsigned short* vp = vt + (((size_t)bh * 64 + w * 16) * 64 + lm) * 32 + quad * 8;

    #pragma unroll 4
    for (int it = 0; it < 16; ++it) {
        // K A-frags: offsets kt*1024 elems (2048B), c*32 elems (64B) -> imm
        bf16x8 kf[2][2];
        #pragma unroll
        for (int kt = 0; kt < 2; ++kt)
            #pragma unroll
            for (int c = 0; c < 2; ++c)
                kf[kt][c] = *(const bf16x8*)(kp + kt * 1024 + c * 32);
        // V B-frags from tiled vt: offsets dt*512 elems (1024B) -> imm; wave load is 1KB contiguous
        bf16x8 vf[4];
        #pragma unroll
        for (int dt = 0; dt < 4; ++dt)
            vf[dt] = *(const bf16x8*)(vp + dt * 512);

        // S^T = K Q^T  (C: col q = lm, row kseq = kt*16 + quad*4 + r)
        #pragma unroll
        for (int kt = 0; kt < 2; ++kt) {
            f32x4 s[4];
            #pragma unroll
            for (int qt = 0; qt < 4; ++qt) {
                f32x4 z = (f32x4){0.f, 0.f, 0.f, 0.f};
                z = __builtin_amdgcn_mfma_f32_16x16x32_bf16(kf[kt][0], qf[qt][0], z, 0, 0, 0);
                s[qt] = __builtin_amdgcn_mfma_f32_16x16x32_bf16(kf[kt][1], qf[qt][1], z, 0, 0, 0);
            }
            #pragma unroll
            for (int qt = 0; qt < 4; ++qt) {
                unsigned int u[4];
                #pragma unroll
                for (int r = 0; r < 4; ++r) {
                    float p = __builtin_amdgcn_exp2f(s[qt][r]);
                    rs[qt] += p;                     // raw p; LDS gets truncated (<=0.1% skew)
                    u[r] = __builtin_bit_cast(unsigned int, p);
                }
                // perm keeps high16 of each pair -> truncation to bf16, packed
                unsigned int lo = __builtin_amdgcn_perm(u[1], u[0], 0x07060302);
                unsigned int hi = __builtin_amdgcn_perm(u[3], u[2], 0x07060302);
                unsigned long long pv = ((unsigned long long)hi << 32) | lo;
                *(unsigned long long*)&myPs[(qt * 16 + lm) * PSW + kt * 16 + quad * 4] = pv;
            }
        }
        // O += P V
        #pragma unroll
        for (int qt = 0; qt < 4; ++qt) {
            bf16x8 pf = *(const bf16x8*)&myPs[(qt * 16 + lm) * PSW + quad * 8];
            #pragma unroll
            for (int dt = 0; dt < 4; ++dt)
                o[qt][dt] = __builtin_amdgcn_mfma_f32_16x16x32_bf16(pf, vf[dt], o[qt][dt], 0, 0, 0);
        }
        kp += 2048;   // 32 kseq rows * 64 d
        vp += 2048;   // one 32-kseq tile
    }

    // reduce rs across quads (value for q-col lm replicated to all quads)
    #pragma unroll
    for (int off = 16; off < 64; off <<= 1)
        #pragma unroll
        for (int qt = 0; qt < 4; ++qt) rs[qt] += __shfl_xor(rs[qt], off, 64);

    // merge the 4 k-groups
    __syncthreads();
    if (w > 0 && quad == 0) {
        #pragma unroll
        for (int qt = 0; qt < 4; ++qt) lRed[(w - 1) * 64 + qt * 16 + lm] = rs[qt];
    }
    __syncthreads();
    if (w == 0) {
        #pragma unroll
        for (int qt = 0; qt < 4; ++qt)
            rs[qt] += lRed[qt * 16 + lm] + lRed[64 + qt * 16 + lm] + lRed[128 + qt * 16 + lm];
    }
    #pragma unroll
    for (int s = 1; s < 4; ++s) {
        __syncthreads();
        if (w == s) {
            #pragma unroll
            for (int qt = 0; qt < 4; ++qt)
                #pragma unroll
                for (int dt = 0; dt < 4; ++dt)
                    #pragma unroll
                    for (int r = 0; r < 4; ++r)
                        oBuf[(qt * 16 + quad * 4 + r) * OPW + dt * 16 + lm] = o[qt][dt][r];
        }
        __syncthreads();
        if (w == 0) {
            #pragma unroll
            for (int qt = 0; qt < 4; ++qt)
                #pragma unroll
                for (int dt = 0; dt < 4; ++dt)
                    #pragma unroll
                    for (int r = 0; r < 4; ++r)
                        o[qt][dt][r] += oBuf[(qt * 16 + quad * 4 + r) * OPW + dt * 16 + lm];
        }
    }
    if (w == 0) {
        #pragma unroll
        for (int qt = 0; qt < 4; ++qt)
            #pragma unroll
            for (int r = 0; r < 4; ++r) {
                float inv = 1.0f / __shfl(rs[qt], quad * 4 + r, 64);
                int row = b * SEQ + q0 + qt * 16 + quad * 4 + r;
                #pragma unroll
                for (int dt = 0; dt < 4; ++dt)
                    attnb[(size_t)row * HID + h * DH + dt * 16 + lm] = f2bf(o[qt][dt][r] * inv);
            }
    }
}

// ========== output GEMM: 64x128 tiles ==========
__global__ __launch_bounds__(256) void gemm_out(const unsigned short* __restrict__ A,
                                                const unsigned short* __restrict__ Bt,
                                                float* __restrict__ C)
{
    __shared__ __align__(16) unsigned short As[64 * 32];
    __shared__ __align__(16) unsigned short Bs[128 * 32];
    const int tid = threadIdx.x;
    const int w = tid >> 6, lane = tid & 63;
    const int quad = lane >> 4, lm = lane & 15;
    const int wr = (w >> 1) * 32, wc = (w & 1) * 64;
    const int bm = blockIdx.y * 64, bn = blockIdx.x * 128;
    const int m0 = tid >> 2;
    const int sk = (tid & 3) << 3;

    f32x4 acc[2][4];
    #pragma unroll
    for (int i = 0; i < 2; ++i)
        #pragma unroll
        for (int j = 0; j < 4; ++j) acc[i][j] = (f32x4){0.f, 0.f, 0.f, 0.f};

    for (int k0 = 0; k0 < 1024; k0 += 32) {
        __syncthreads();
        gload_lds16(&A [(size_t)(bm + m0     ) * 1024 + k0 + sk], As + (size_t)w * 512);
        gload_lds16(&Bt[(size_t)(bn + m0     ) * 1024 + k0 + sk], Bs + (size_t)w * 512);
        gload_lds16(&Bt[(size_t)(bn + m0 + 64) * 1024 + k0 + sk], Bs + 2048 + (size_t)w * 512);
        __syncthreads();
        bf16x8 af[2], bfr[4];
        #pragma unroll
        for (int mt = 0; mt < 2; ++mt) af[mt] = *(const bf16x8*)&As[(wr + mt * 16 + lm) * 32 + quad * 8];
        #pragma unroll
        for (int nt = 0; nt < 4; ++nt) bfr[nt] = *(const bf16x8*)&Bs[(wc + nt * 16 + lm) * 32 + quad * 8];
        #pragma unroll
        for (int mt = 0; mt < 2; ++mt)
            #pragma unroll
            for (int nt = 0; nt < 4; ++nt)
                acc[mt][nt] = __builtin_amdgcn_mfma_f32_16x16x32_bf16(af[mt], bfr[nt], acc[mt][nt], 0, 0, 0);
    }

    #pragma unroll
    for (int mt = 0; mt < 2; ++mt)
        #pragma unroll
        for (int nt = 0; nt < 4; ++nt) {
            int col = bn + wc + nt * 16 + lm;
            #pragma unroll
            for (int r = 0; r < 4; ++r) {
                int row = bm + wr + mt * 16 + quad * 4 + r;
                C[(size_t)row * 1024 + col] = acc[mt][nt][r];
            }
        }
}

extern "C" void kernel_launch(void* const* d_in, const int* in_sizes, int n_in,
                              void* d_out, int out_size, void* d_ws, size_t ws_size,
                              hipStream_t stream) {
    const float* x     = (const float*)d_in[0];
    const float* rot   = (const float*)d_in[1];
    const float* w_qkv = (const float*)d_in[2];
    const float* w_out = (const float*)d_in[3];
    float* out = (float*)d_out;

    char* ws = (char*)d_ws;
    unsigned short* xb    = (unsigned short*)(ws);                         // 8 MB
    unsigned short* qb    = (unsigned short*)(ws + (size_t)( 8u << 20));   // 8 MB [bh][seq][64]
    unsigned short* kb    = (unsigned short*)(ws + (size_t)(16u << 20));   // 8 MB [bh][seq][64]
    unsigned short* vt    = (unsigned short*)(ws + (size_t)(24u << 20));   // 8 MB [bh][seq/32][64][32]
    unsigned short* attnb = (unsigned short*)(ws + (size_t)(32u << 20));   // 8 MB
    unsigned short* wqkvT = (unsigned short*)(ws + (size_t)(40u << 20));   // 6 MB
    unsigned short* woutT = (unsigned short*)(ws + (size_t)(46u << 20));   // 2 MB
    float2*         ctab  = (float2*)        (ws + (size_t)(48u << 20));   // 1 MB

    prep<<<3584, 256, 0, stream>>>(x, rot, w_qkv, w_out, xb, ctab, wqkvT, woutT);

    gemm_qkv<<<dim3(24, 32), 256, 0, stream>>>(xb, wqkvT, ctab, qb, kb, vt);

    attn6<<<dim3(SEQ / 64, 32), 256, 0, stream>>>(qb, kb, vt, attnb);

    gemm_out<<<dim3(8, 64), 256, 0, stream>>>(attnb, woutT, out);
}

// Round 9
// 210.152 us; speedup vs baseline: 1.1501x; 1.0078x over previous
//
#include <hip/hip_runtime.h>
#include <math.h>

#define HEADS 16
#define DH    64
#define SEQ   2048
#define HID   1024
#define NROW  4096

typedef __attribute__((ext_vector_type(8))) short bf16x8;
typedef __attribute__((ext_vector_type(4))) float f32x4;

#define AS1 __attribute__((address_space(1)))
#define AS3 __attribute__((address_space(3)))

// 0.125 * log2(e): folds softmax scale and exp->exp2 into the Q pack.
#define QSCALE 0.18033688011112042f

__device__ __forceinline__ unsigned short f2bf(float x) {
    unsigned int u = __builtin_bit_cast(unsigned int, x);
    u = (u + 0x7FFFu + ((u >> 16) & 1u)) >> 16;
    return (unsigned short)u;
}

__device__ __forceinline__ void gload_lds16(const unsigned short* g, unsigned short* l) {
    __builtin_amdgcn_global_load_lds((AS1 void*)g, (AS3 void*)l, 16, 0, 0);
}

// ================= prep: conv_x + rope_tab + 2x wtrans in ONE launch =================
__device__ void wtrans_body(const float* __restrict__ wsrc, unsigned short* __restrict__ wt,
                            int K, int N, int bx, int by, float (*T)[65])
{
    const int tid = threadIdx.x;
    const int k0 = by * 64, n0 = bx * 64;
    #pragma unroll
    for (int rnd = 0; rnd < 4; ++rnd) {
        int row = (tid >> 4) + rnd * 16;
        int c = (tid & 15) * 4;
        float4 v = *(const float4*)&wsrc[(size_t)(k0 + row) * N + n0 + c];
        T[row][c] = v.x; T[row][c+1] = v.y; T[row][c+2] = v.z; T[row][c+3] = v.w;
    }
    __syncthreads();
    const int sr = tid >> 3, sc = (tid & 7) << 3;
    #pragma unroll
    for (int half = 0; half < 2; ++half) {
        int n = sr + half * 32;
        union { unsigned short u[8]; bf16x8 v; } pk;
        #pragma unroll
        for (int j = 0; j < 8; ++j) pk.u[j] = f2bf(T[sc + j][n]);
        *(bf16x8*)&wt[(size_t)(n0 + n) * K + k0 + sc] = pk.v;
    }
}

__global__ __launch_bounds__(256) void prep(const float* __restrict__ x,
                                            const float* __restrict__ rot,
                                            const float* __restrict__ w_qkv,
                                            const float* __restrict__ w_out,
                                            unsigned short* __restrict__ xb,
                                            float2* __restrict__ ctab,
                                            unsigned short* __restrict__ wqkvT,
                                            unsigned short* __restrict__ woutT)
{
    __shared__ float T[64][65];
    const int bid = blockIdx.x;
    if (bid < 2048) {
        size_t i = ((size_t)bid * 256 + threadIdx.x) * 8;
        float4 a = *(const float4*)&x[i];
        float4 b = *(const float4*)&x[i + 4];
        union { unsigned short u[8]; bf16x8 v; } pk;
        pk.u[0] = f2bf(a.x); pk.u[1] = f2bf(a.y); pk.u[2] = f2bf(a.z); pk.u[3] = f2bf(a.w);
        pk.u[4] = f2bf(b.x); pk.u[5] = f2bf(b.y); pk.u[6] = f2bf(b.z); pk.u[7] = f2bf(b.w);
        *(bf16x8*)&xb[i] = pk.v;
    } else if (bid < 2560) {
        int i = (bid - 2048) * 256 + threadIdx.x;   // SEQ*DH = 131072
        float r = rot[i];
        float s, c;
        __sincosf(r, &s, &c);
        ctab[i] = make_float2(c, s);
    } else if (bid < 3328) {
        int idx = bid - 2560;                       // 48 x 16
        wtrans_body(w_qkv, wqkvT, 1024, 3072, idx % 48, idx / 48, T);
    } else {
        int idx = bid - 3328;                       // 16 x 16
        wtrans_body(w_out, woutT, 1024, 1024, idx % 16, idx / 16, T);
    }
}

// ========== QKV GEMM, BK=32, fused RoPE/split epilogue ==========
// V written to TILED layout: vt[bh][t=seq/32][d=64][ks=32]
__global__ __launch_bounds__(256) void gemm_qkv(const unsigned short* __restrict__ A,
                                                const unsigned short* __restrict__ Bt,
                                                const float2* __restrict__ ctab,
                                                unsigned short* __restrict__ qb,
                                                unsigned short* __restrict__ kb,
                                                unsigned short* __restrict__ vt)
{
    __shared__ __align__(16) unsigned short As[128 * 32];
    __shared__ __align__(16) unsigned short Bs[128 * 32];
    const int tid = threadIdx.x;
    const int w = tid >> 6, lane = tid & 63;
    const int quad = lane >> 4, lm = lane & 15;
    const int wr = (w >> 1) * 64, wc = (w & 1) * 64;
    const int bm = blockIdx.y * 128, bn = blockIdx.x * 128;
    const int m0 = tid >> 2;
    const int sk = (tid & 3) << 3;

    f32x4 acc[4][4];
    #pragma unroll
    for (int i = 0; i < 4; ++i)
        #pragma unroll
        for (int j = 0; j < 4; ++j) acc[i][j] = (f32x4){0.f, 0.f, 0.f, 0.f};

    for (int k0 = 0; k0 < 1024; k0 += 32) {
        __syncthreads();
        gload_lds16(&A [(size_t)(bm + m0     ) * 1024 + k0 + sk], As + (size_t)w * 512);
        gload_lds16(&A [(size_t)(bm + m0 + 64) * 1024 + k0 + sk], As + 2048 + (size_t)w * 512);
        gload_lds16(&Bt[(size_t)(bn + m0     ) * 1024 + k0 + sk], Bs + (size_t)w * 512);
        gload_lds16(&Bt[(size_t)(bn + m0 + 64) * 1024 + k0 + sk], Bs + 2048 + (size_t)w * 512);
        __syncthreads();
        bf16x8 af[4], bfr[4];
        #pragma unroll
        for (int mt = 0; mt < 4; ++mt) af[mt] = *(const bf16x8*)&As[(wr + mt * 16 + lm) * 32 + quad * 8];
        #pragma unroll
        for (int nt = 0; nt < 4; ++nt) bfr[nt] = *(const bf16x8*)&Bs[(wc + nt * 16 + lm) * 32 + quad * 8];
        #pragma unroll
        for (int mt = 0; mt < 4; ++mt)
            #pragma unroll
            for (int nt = 0; nt < 4; ++nt)
                acc[mt][nt] = __builtin_amdgcn_mfma_f32_16x16x32_bf16(af[mt], bfr[nt], acc[mt][nt], 0, 0, 0);
    }

    const int colbase = bn + wc;
    const int region = colbase >> 10;      // 0=q, 1=k, 2=v
    const int h = (colbase >> 6) & 15;

    if (region == 2) {
        #pragma unroll
        for (int mt = 0; mt < 4; ++mt) {
            int rowb = bm + wr + mt * 16 + quad * 4;
            int b = rowb >> 11, seq = rowb & (SEQ - 1);
            int t = seq >> 5, ks = seq & 31;
            #pragma unroll
            for (int nt = 0; nt < 4; ++nt) {
                int d = nt * 16 + lm;
                ushort4 pk;
                pk.x = f2bf(acc[mt][nt][0]); pk.y = f2bf(acc[mt][nt][1]);
                pk.z = f2bf(acc[mt][nt][2]); pk.w = f2bf(acc[mt][nt][3]);
                *(ushort4*)&vt[(((size_t)(b * HEADS + h) * 64 + t) * 64 + d) * 32 + ks] = pk;
            }
        }
    } else {
        const float qs = (region == 0) ? QSCALE : 1.0f;
        unsigned short* dst = (region == 0) ? qb : kb;
        #pragma unroll
        for (int mt = 0; mt < 4; ++mt) {
            #pragma unroll
            for (int nt = 0; nt < 2; ++nt) {
                int d = nt * 16 + lm;
                #pragma unroll
                for (int r = 0; r < 4; ++r) {
                    int row = bm + wr + mt * 16 + quad * 4 + r;
                    int b = row >> 11, seq = row & (SEQ - 1);
                    float2 cs0 = ctab[seq * DH + d];
                    float2 cs1 = ctab[seq * DH + d + 32];
                    float x0 = acc[mt][nt][r];
                    float x1 = acc[mt][nt + 2][r];
                    size_t ob = ((size_t)(b * HEADS + h) * SEQ + seq) * DH;
                    dst[ob + d]      = f2bf((x0 * cs0.x - x1 * cs0.y) * qs);
                    dst[ob + d + 32] = f2bf((x1 * cs1.x + x0 * cs1.y) * qs);
                }
            }
        }
    }
}

// ========== Flash attention v9b: DMA-staged K/V double-buffer, XOR-swizzled K, ==========
// ========== 64 q/wave, barrier-before-issue prefetch, 2-way K-split merge      ==========
// 256 thr = 4 waves: wave = (qg = w>>1, kg = w&1). Block covers 128 q; per iter
// stages 64 kseq (K 8KB swizzled + V 8KB tiled); wave computes its 32-kseq half
// against its 64 q. grid (SEQ/128, BSZ*HEADS) = 512 blocks = 2/CU.
#define PSW9 36
__global__ __launch_bounds__(256, 2) void attn9(const unsigned short* __restrict__ qb,
                                                const unsigned short* __restrict__ kb,
                                                const unsigned short* __restrict__ vt,
                                                unsigned short* __restrict__ attnb)
{
    __shared__ __align__(16) char smem[51200];
    unsigned short* Ks = (unsigned short*)smem;             // [2 buf][64 kseq][64 d] swizzled, 16384 B
    unsigned short* Vs = (unsigned short*)(smem + 16384);   // [2 buf][2 t][64 d][32 ks], 16384 B
    unsigned short* Ps = (unsigned short*)(smem + 32768);   // [4 wave][64 q][PSW9], 18432 B

    const int tid = threadIdx.x;
    const int w = tid >> 6, lane = tid & 63, quad = lane >> 4, lm = lane & 15;
    const int qg = w >> 1, kg = w & 1;
    const int bh = blockIdx.y, q0 = blockIdx.x * 128;
    const int b = bh >> 4, h = bh & 15;
    const size_t hb = (size_t)bh * SEQ * DH;
    unsigned short* myPs = Ps + w * (64 * PSW9);

    // Q fragments: wave's 64 q rows (B-operand: lane q=lm, k = c*32+quad*8+j)
    bf16x8 qf[4][2];
    #pragma unroll
    for (int qt = 0; qt < 4; ++qt)
        #pragma unroll
        for (int c = 0; c < 2; ++c)
            qf[qt][c] = *(const bf16x8*)&qb[hb + (size_t)(q0 + qg * 64 + qt * 16 + lm) * DH + c * 32 + quad * 8];

    // --- staging lane constants ---
    // K: chunk ci = w*128 + n*64 + lane; r = ci>>3; p = ci&7; logical chunk l = p^(r&7)
    const int r0 = (w * 16) + (lane >> 3);
    const int p0 = lane & 7;
    const int gk0 = r0 * 64 + (p0 ^ (r0 & 7)) * 8;          // global elem offset within tile, n=0
    const int r1 = r0 + 8;
    const int gk1 = r1 * 64 + (p0 ^ (r1 & 7)) * 8;          // n=1
    const unsigned short* kgp = kb + hb;
    const unsigned short* vgp = vt + hb;                     // tiled [t][64][32]
    const int gv0 = w * 1024 + lane * 8;                     // V natural chunks within tile
    const int gv1 = gv0 + 512;
    unsigned short* kdst0 = Ks + w * 1024;                   // + buf*4096, lane*16B auto
    unsigned short* kdst1 = Ks + w * 1024 + 512;
    unsigned short* vdst0 = Vs + w * 1024;
    unsigned short* vdst1 = Vs + w * 1024 + 512;

    // --- frag read offsets (elements, relative to buffer base) ---
    int kfo[2];
    #pragma unroll
    for (int c = 0; c < 2; ++c)
        kfo[c] = (kg * 32 + lm) * 64 + (((c * 4 + quad) ^ (lm & 7)) * 8);
    const int vfo = kg * 2048 + lm * 32 + quad * 8;          // + dt*512

    float rs[4] = {0.f, 0.f, 0.f, 0.f};
    f32x4 o[4][4];
    #pragma unroll
    for (int qt = 0; qt < 4; ++qt)
        #pragma unroll
        for (int dt = 0; dt < 4; ++dt) o[qt][dt] = (f32x4){0.f, 0.f, 0.f, 0.f};

    // prime: DMA tile 0 into buf 0
    gload_lds16(kgp + gk0, kdst0);
    gload_lds16(kgp + gk1, kdst1);
    gload_lds16(vgp + gv0, vdst0);
    gload_lds16(vgp + gv1, vdst1);

    #pragma unroll 2
    for (int it = 0; it < 32; ++it) {
        const int buf = it & 1;
        __syncthreads();   // drains vmcnt(0): DMA(it) visible to all; buf^1 free to overwrite
        {
            // FIX(R8): tile base in ELEMENTS = tile_index * 64 rows * 64 d = *4096
            const size_t nb = (size_t)((it + 1) & 31) * 4096;
            const int bo = (buf ^ 1) * 4096;
            gload_lds16(kgp + nb + gk0, kdst0 + bo);
            gload_lds16(kgp + nb + gk1, kdst1 + bo);
            gload_lds16(vgp + nb + gv0, vdst0 + bo);
            gload_lds16(vgp + nb + gv1, vdst1 + bo);
        }
        const unsigned short* Kb = Ks + buf * 4096;
        const unsigned short* Vb = Vs + buf * 4096;

        bf16x8 vf[4];
        #pragma unroll
        for (int dt = 0; dt < 4; ++dt)
            vf[dt] = *(const bf16x8*)&Vb[vfo + dt * 512];

        #pragma unroll
        for (int kt = 0; kt < 2; ++kt) {
            bf16x8 k0 = *(const bf16x8*)&Kb[kfo[0] + kt * 1024];
            bf16x8 k1 = *(const bf16x8*)&Kb[kfo[1] + kt * 1024];
            f32x4 s[4];
            #pragma unroll
            for (int qt = 0; qt < 4; ++qt) {
                f32x4 z = (f32x4){0.f, 0.f, 0.f, 0.f};
                z = __builtin_amdgcn_mfma_f32_16x16x32_bf16(k0, qf[qt][0], z, 0, 0, 0);
                s[qt] = __builtin_amdgcn_mfma_f32_16x16x32_bf16(k1, qf[qt][1], z, 0, 0, 0);
            }
            #pragma unroll
            for (int qt = 0; qt < 4; ++qt) {
                unsigned int u[4];
                #pragma unroll
                for (int r = 0; r < 4; ++r) {
                    float p = __builtin_amdgcn_exp2f(s[qt][r]);
                    rs[qt] += p;
                    u[r] = __builtin_bit_cast(unsigned int, p);
                }
                unsigned int lo = __builtin_amdgcn_perm(u[1], u[0], 0x07060302);
                unsigned int hi = __builtin_amdgcn_perm(u[3], u[2], 0x07060302);
                unsigned long long pv = ((unsigned long long)hi << 32) | lo;
                *(unsigned long long*)&myPs[(qt * 16 + lm) * PSW9 + kt * 16 + quad * 4] = pv;
            }
        }
        // O += P V   (A = P[q][k32] wave-private, B = vf; contraction = this wave's 32 kseq)
        #pragma unroll
        for (int qt = 0; qt < 4; ++qt) {
            bf16x8 pf = *(const bf16x8*)&myPs[(qt * 16 + lm) * PSW9 + quad * 8];
            #pragma unroll
            for (int dt = 0; dt < 4; ++dt)
                o[qt][dt] = __builtin_amdgcn_mfma_f32_16x16x32_bf16(pf, vf[dt], o[qt][dt], 0, 0, 0);
        }
    }

    // quad-reduce rs (value for q = qt*16+lm, replicated across quads)
    #pragma unroll
    for (int off = 16; off < 64; off <<= 1)
        #pragma unroll
        for (int qt = 0; qt < 4; ++qt) rs[qt] += __shfl_xor(rs[qt], off, 64);

    // ---- merge the 2 k-groups (linear softmax: plain add) ----
    __syncthreads();
    float* oBuf = (float*)smem;                  // [2 qg][64 q][68], 34816 B (overlays Ks/Vs/Ps)
    float* lRed = (float*)(smem + 40960);        // [2 qg][64]
    if (kg == 1) {
        #pragma unroll
        for (int qt = 0; qt < 4; ++qt)
            #pragma unroll
            for (int dt = 0; dt < 4; ++dt)
                #pragma unroll
                for (int r = 0; r < 4; ++r)
                    oBuf[(qg * 64 + qt * 16 + quad * 4 + r) * 68 + dt * 16 + lm] = o[qt][dt][r];
        if (quad == 0) {
            #pragma unroll
            for (int qt = 0; qt < 4; ++qt) lRed[qg * 64 + qt * 16 + lm] = rs[qt];
        }
    }
    __syncthreads();
    if (kg == 0) {
        #pragma unroll
        for (int qt = 0; qt < 4; ++qt) {
            rs[qt] += lRed[qg * 64 + qt * 16 + lm];
            #pragma unroll
            for (int dt = 0; dt < 4; ++dt)
                #pragma unroll
                for (int r = 0; r < 4; ++r)
                    o[qt][dt][r] += oBuf[(qg * 64 + qt * 16 + quad * 4 + r) * 68 + dt * 16 + lm];
        }
        #pragma unroll
        for (int qt = 0; qt < 4; ++qt)
            #pragma unroll
            for (int r = 0; r < 4; ++r) {
                float inv = 1.0f / __shfl(rs[qt], quad * 4 + r, 64);
                int row = b * SEQ + q0 + qg * 64 + qt * 16 + quad * 4 + r;
                #pragma unroll
                for (int dt = 0; dt < 4; ++dt)
                    attnb[(size_t)row * HID + h * DH + dt * 16 + lm] = f2bf(o[qt][dt][r] * inv);
            }
    }
}

// ========== output GEMM: 64x128 tiles ==========
__global__ __launch_bounds__(256) void gemm_out(const unsigned short* __restrict__ A,
                                                const unsigned short* __restrict__ Bt,
                                                float* __restrict__ C)
{
    __shared__ __align__(16) unsigned short As[64 * 32];
    __shared__ __align__(16) unsigned short Bs[128 * 32];
    const int tid = threadIdx.x;
    const int w = tid >> 6, lane = tid & 63;
    const int quad = lane >> 4, lm = lane & 15;
    const int wr = (w >> 1) * 32, wc = (w & 1) * 64;
    const int bm = blockIdx.y * 64, bn = blockIdx.x * 128;
    const int m0 = tid >> 2;
    const int sk = (tid & 3) << 3;

    f32x4 acc[2][4];
    #pragma unroll
    for (int i = 0; i < 2; ++i)
        #pragma unroll
        for (int j = 0; j < 4; ++j) acc[i][j] = (f32x4){0.f, 0.f, 0.f, 0.f};

    for (int k0 = 0; k0 < 1024; k0 += 32) {
        __syncthreads();
        gload_lds16(&A [(size_t)(bm + m0     ) * 1024 + k0 + sk], As + (size_t)w * 512);
        gload_lds16(&Bt[(size_t)(bn + m0     ) * 1024 + k0 + sk], Bs + (size_t)w * 512);
        gload_lds16(&Bt[(size_t)(bn + m0 + 64) * 1024 + k0 + sk], Bs + 2048 + (size_t)w * 512);
        __syncthreads();
        bf16x8 af[2], bfr[4];
        #pragma unroll
        for (int mt = 0; mt < 2; ++mt) af[mt] = *(const bf16x8*)&As[(wr + mt * 16 + lm) * 32 + quad * 8];
        #pragma unroll
        for (int nt = 0; nt < 4; ++nt) bfr[nt] = *(const bf16x8*)&Bs[(wc + nt * 16 + lm) * 32 + quad * 8];
        #pragma unroll
        for (int mt = 0; mt < 2; ++mt)
            #pragma unroll
            for (int nt = 0; nt < 4; ++nt)
                acc[mt][nt] = __builtin_amdgcn_mfma_f32_16x16x32_bf16(af[mt], bfr[nt], acc[mt][nt], 0, 0, 0);
    }

    #pragma unroll
    for (int mt = 0; mt < 2; ++mt)
        #pragma unroll
        for (int nt = 0; nt < 4; ++nt) {
            int col = bn + wc + nt * 16 + lm;
            #pragma unroll
            for (int r = 0; r < 4; ++r) {
                int row = bm + wr + mt * 16 + quad * 4 + r;
                C[(size_t)row * 1024 + col] = acc[mt][nt][r];
            }
        }
}

extern "C" void kernel_launch(void* const* d_in, const int* in_sizes, int n_in,
                              void* d_out, int out_size, void* d_ws, size_t ws_size,
                              hipStream_t stream) {
    const float* x     = (const float*)d_in[0];
    const float* rot   = (const float*)d_in[1];
    const float* w_qkv = (const float*)d_in[2];
    const float* w_out = (const float*)d_in[3];
    float* out = (float*)d_out;

    char* ws = (char*)d_ws;
    unsigned short* xb    = (unsigned short*)(ws);                         // 8 MB
    unsigned short* qb    = (unsigned short*)(ws + (size_t)( 8u << 20));   // 8 MB [bh][seq][64]
    unsigned short* kb    = (unsigned short*)(ws + (size_t)(16u << 20));   // 8 MB [bh][seq][64]
    unsigned short* vt    = (unsigned short*)(ws + (size_t)(24u << 20));   // 8 MB [bh][seq/32][64][32]
    unsigned short* attnb = (unsigned short*)(ws + (size_t)(32u << 20));   // 8 MB
    unsigned short* wqkvT = (unsigned short*)(ws + (size_t)(40u << 20));   // 6 MB
    unsigned short* woutT = (unsigned short*)(ws + (size_t)(46u << 20));   // 2 MB
    float2*         ctab  = (float2*)        (ws + (size_t)(48u << 20));   // 1 MB

    prep<<<3584, 256, 0, stream>>>(x, rot, w_qkv, w_out, xb, ctab, wqkvT, woutT);

    gemm_qkv<<<dim3(24, 32), 256, 0, stream>>>(xb, wqkvT, ctab, qb, kb, vt);

    attn9<<<dim3(SEQ / 128, 32), 256, 0, stream>>>(qb, kb, vt, attnb);

    gemm_out<<<dim3(8, 64), 256, 0, stream>>>(attnb, woutT, out);
}

// Round 10
// 209.979 us; speedup vs baseline: 1.1510x; 1.0008x over previous
//
#include <hip/hip_runtime.h>
#include <math.h>

#define HEADS 16
#define DH    64
#define SEQ   2048
#define HID   1024
#define NROW  4096

typedef __attribute__((ext_vector_type(8))) short bf16x8;
typedef __attribute__((ext_vector_type(4))) float f32x4;

#define AS1 __attribute__((address_space(1)))
#define AS3 __attribute__((address_space(3)))

// 0.125 * log2(e): folds softmax scale and exp->exp2 into the Q pack.
#define QSCALE 0.18033688011112042f

__device__ __forceinline__ unsigned short f2bf(float x) {
    unsigned int u = __builtin_bit_cast(unsigned int, x);
    u = (u + 0x7FFFu + ((u >> 16) & 1u)) >> 16;
    return (unsigned short)u;
}

__device__ __forceinline__ void gload_lds16(const unsigned short* g, unsigned short* l) {
    __builtin_amdgcn_global_load_lds((AS1 void*)g, (AS3 void*)l, 16, 0, 0);
}

// ================= prep: conv_x + rope_tab + 2x wtrans in ONE launch =================
__device__ void wtrans_body(const float* __restrict__ wsrc, unsigned short* __restrict__ wt,
                            int K, int N, int bx, int by, float (*T)[65])
{
    const int tid = threadIdx.x;
    const int k0 = by * 64, n0 = bx * 64;
    #pragma unroll
    for (int rnd = 0; rnd < 4; ++rnd) {
        int row = (tid >> 4) + rnd * 16;
        int c = (tid & 15) * 4;
        float4 v = *(const float4*)&wsrc[(size_t)(k0 + row) * N + n0 + c];
        T[row][c] = v.x; T[row][c+1] = v.y; T[row][c+2] = v.z; T[row][c+3] = v.w;
    }
    __syncthreads();
    const int sr = tid >> 3, sc = (tid & 7) << 3;
    #pragma unroll
    for (int half = 0; half < 2; ++half) {
        int n = sr + half * 32;
        union { unsigned short u[8]; bf16x8 v; } pk;
        #pragma unroll
        for (int j = 0; j < 8; ++j) pk.u[j] = f2bf(T[sc + j][n]);
        *(bf16x8*)&wt[(size_t)(n0 + n) * K + k0 + sc] = pk.v;
    }
}

__global__ __launch_bounds__(256) void prep(const float* __restrict__ x,
                                            const float* __restrict__ rot,
                                            const float* __restrict__ w_qkv,
                                            const float* __restrict__ w_out,
                                            unsigned short* __restrict__ xb,
                                            float2* __restrict__ ctab,
                                            unsigned short* __restrict__ wqkvT,
                                            unsigned short* __restrict__ woutT)
{
    __shared__ float T[64][65];
    const int bid = blockIdx.x;
    if (bid < 2048) {
        size_t i = ((size_t)bid * 256 + threadIdx.x) * 8;
        float4 a = *(const float4*)&x[i];
        float4 b = *(const float4*)&x[i + 4];
        union { unsigned short u[8]; bf16x8 v; } pk;
        pk.u[0] = f2bf(a.x); pk.u[1] = f2bf(a.y); pk.u[2] = f2bf(a.z); pk.u[3] = f2bf(a.w);
        pk.u[4] = f2bf(b.x); pk.u[5] = f2bf(b.y); pk.u[6] = f2bf(b.z); pk.u[7] = f2bf(b.w);
        *(bf16x8*)&xb[i] = pk.v;
    } else if (bid < 2560) {
        int i = (bid - 2048) * 256 + threadIdx.x;   // SEQ*DH = 131072
        float r = rot[i];
        float s, c;
        __sincosf(r, &s, &c);
        ctab[i] = make_float2(c, s);
    } else if (bid < 3328) {
        int idx = bid - 2560;                       // 48 x 16
        wtrans_body(w_qkv, wqkvT, 1024, 3072, idx % 48, idx / 48, T);
    } else {
        int idx = bid - 3328;                       // 16 x 16
        wtrans_body(w_out, woutT, 1024, 1024, idx % 16, idx / 16, T);
    }
}

// ========== QKV GEMM, BK=32, fused RoPE/split epilogue ==========
// V written to TILED layout: vt[bh][t=seq/32][d=64][ks=32]
__global__ __launch_bounds__(256) void gemm_qkv(const unsigned short* __restrict__ A,
                                                const unsigned short* __restrict__ Bt,
                                                const float2* __restrict__ ctab,
                                                unsigned short* __restrict__ qb,
                                                unsigned short* __restrict__ kb,
                                                unsigned short* __restrict__ vt)
{
    __shared__ __align__(16) unsigned short As[128 * 32];
    __shared__ __align__(16) unsigned short Bs[128 * 32];
    const int tid = threadIdx.x;
    const int w = tid >> 6, lane = tid & 63;
    const int quad = lane >> 4, lm = lane & 15;
    const int wr = (w >> 1) * 64, wc = (w & 1) * 64;
    const int bm = blockIdx.y * 128, bn = blockIdx.x * 128;
    const int m0 = tid >> 2;
    const int sk = (tid & 3) << 3;

    f32x4 acc[4][4];
    #pragma unroll
    for (int i = 0; i < 4; ++i)
        #pragma unroll
        for (int j = 0; j < 4; ++j) acc[i][j] = (f32x4){0.f, 0.f, 0.f, 0.f};

    for (int k0 = 0; k0 < 1024; k0 += 32) {
        __syncthreads();
        gload_lds16(&A [(size_t)(bm + m0     ) * 1024 + k0 + sk], As + (size_t)w * 512);
        gload_lds16(&A [(size_t)(bm + m0 + 64) * 1024 + k0 + sk], As + 2048 + (size_t)w * 512);
        gload_lds16(&Bt[(size_t)(bn + m0     ) * 1024 + k0 + sk], Bs + (size_t)w * 512);
        gload_lds16(&Bt[(size_t)(bn + m0 + 64) * 1024 + k0 + sk], Bs + 2048 + (size_t)w * 512);
        __syncthreads();
        bf16x8 af[4], bfr[4];
        #pragma unroll
        for (int mt = 0; mt < 4; ++mt) af[mt] = *(const bf16x8*)&As[(wr + mt * 16 + lm) * 32 + quad * 8];
        #pragma unroll
        for (int nt = 0; nt < 4; ++nt) bfr[nt] = *(const bf16x8*)&Bs[(wc + nt * 16 + lm) * 32 + quad * 8];
        #pragma unroll
        for (int mt = 0; mt < 4; ++mt)
            #pragma unroll
            for (int nt = 0; nt < 4; ++nt)
                acc[mt][nt] = __builtin_amdgcn_mfma_f32_16x16x32_bf16(af[mt], bfr[nt], acc[mt][nt], 0, 0, 0);
    }

    const int colbase = bn + wc;
    const int region = colbase >> 10;      // 0=q, 1=k, 2=v
    const int h = (colbase >> 6) & 15;

    if (region == 2) {
        #pragma unroll
        for (int mt = 0; mt < 4; ++mt) {
            int rowb = bm + wr + mt * 16 + quad * 4;
            int b = rowb >> 11, seq = rowb & (SEQ - 1);
            int t = seq >> 5, ks = seq & 31;
            #pragma unroll
            for (int nt = 0; nt < 4; ++nt) {
                int d = nt * 16 + lm;
                ushort4 pk;
                pk.x = f2bf(acc[mt][nt][0]); pk.y = f2bf(acc[mt][nt][1]);
                pk.z = f2bf(acc[mt][nt][2]); pk.w = f2bf(acc[mt][nt][3]);
                *(ushort4*)&vt[(((size_t)(b * HEADS + h) * 64 + t) * 64 + d) * 32 + ks] = pk;
            }
        }
    } else {
        const float qs = (region == 0) ? QSCALE : 1.0f;
        unsigned short* dst = (region == 0) ? qb : kb;
        #pragma unroll
        for (int mt = 0; mt < 4; ++mt) {
            #pragma unroll
            for (int nt = 0; nt < 2; ++nt) {
                int d = nt * 16 + lm;
                #pragma unroll
                for (int r = 0; r < 4; ++r) {
                    int row = bm + wr + mt * 16 + quad * 4 + r;
                    int b = row >> 11, seq = row & (SEQ - 1);
                    float2 cs0 = ctab[seq * DH + d];
                    float2 cs1 = ctab[seq * DH + d + 32];
                    float x0 = acc[mt][nt][r];
                    float x1 = acc[mt][nt + 2][r];
                    size_t ob = ((size_t)(b * HEADS + h) * SEQ + seq) * DH;
                    dst[ob + d]      = f2bf((x0 * cs0.x - x1 * cs0.y) * qs);
                    dst[ob + d + 32] = f2bf((x1 * cs1.x + x0 * cs1.y) * qs);
                }
            }
        }
    }
}

// ========== Flash attention v10: v9b + XCD-aware block swizzle for K/V L2 locality ==========
// All 16 q-tiles of one (b,h) map to the same XCD (round-robin linear-id assumption):
// L = x + 16y; xcd = L&7; bh = xcd + 8*((L>>3)&3); qt = L>>5.
// Per-XCD K/V working set = 4 bh x 512 KB = 2 MB < 4 MB L2 -> staging DMA hits L2,
// whose ~200-300 cyc latency fits inside the one-compute-phase prefetch window.
#define PSW9 36
__global__ __launch_bounds__(256, 2) void attn9(const unsigned short* __restrict__ qb,
                                                const unsigned short* __restrict__ kb,
                                                const unsigned short* __restrict__ vt,
                                                unsigned short* __restrict__ attnb)
{
    __shared__ __align__(16) char smem[51200];
    unsigned short* Ks = (unsigned short*)smem;             // [2 buf][64 kseq][64 d] swizzled, 16384 B
    unsigned short* Vs = (unsigned short*)(smem + 16384);   // [2 buf][2 t][64 d][32 ks], 16384 B
    unsigned short* Ps = (unsigned short*)(smem + 32768);   // [4 wave][64 q][PSW9], 18432 B

    const int tid = threadIdx.x;
    const int w = tid >> 6, lane = tid & 63, quad = lane >> 4, lm = lane & 15;
    const int qg = w >> 1, kg = w & 1;

    // XCD-aware remap (dispatch-linear L = x + 16*y; HW round-robins L % 8 over XCDs)
    const int L = blockIdx.x + blockIdx.y * 16;
    const int bh = (L & 7) + 8 * ((L >> 3) & 3);
    const int q0 = (L >> 5) * 128;

    const int b = bh >> 4, h = bh & 15;
    const size_t hb = (size_t)bh * SEQ * DH;
    unsigned short* myPs = Ps + w * (64 * PSW9);

    // Q fragments: wave's 64 q rows (B-operand: lane q=lm, k = c*32+quad*8+j)
    bf16x8 qf[4][2];
    #pragma unroll
    for (int qt = 0; qt < 4; ++qt)
        #pragma unroll
        for (int c = 0; c < 2; ++c)
            qf[qt][c] = *(const bf16x8*)&qb[hb + (size_t)(q0 + qg * 64 + qt * 16 + lm) * DH + c * 32 + quad * 8];

    // --- staging lane constants ---
    const int r0 = (w * 16) + (lane >> 3);
    const int p0 = lane & 7;
    const int gk0 = r0 * 64 + (p0 ^ (r0 & 7)) * 8;          // global elem offset within tile, n=0
    const int r1 = r0 + 8;
    const int gk1 = r1 * 64 + (p0 ^ (r1 & 7)) * 8;          // n=1
    const unsigned short* kgp = kb + hb;
    const unsigned short* vgp = vt + hb;                     // tiled [t][64][32]
    const int gv0 = w * 1024 + lane * 8;
    const int gv1 = gv0 + 512;
    unsigned short* kdst0 = Ks + w * 1024;
    unsigned short* kdst1 = Ks + w * 1024 + 512;
    unsigned short* vdst0 = Vs + w * 1024;
    unsigned short* vdst1 = Vs + w * 1024 + 512;

    // --- frag read offsets (elements, relative to buffer base) ---
    int kfo[2];
    #pragma unroll
    for (int c = 0; c < 2; ++c)
        kfo[c] = (kg * 32 + lm) * 64 + (((c * 4 + quad) ^ (lm & 7)) * 8);
    const int vfo = kg * 2048 + lm * 32 + quad * 8;          // + dt*512

    float rs[4] = {0.f, 0.f, 0.f, 0.f};
    f32x4 o[4][4];
    #pragma unroll
    for (int qt = 0; qt < 4; ++qt)
        #pragma unroll
        for (int dt = 0; dt < 4; ++dt) o[qt][dt] = (f32x4){0.f, 0.f, 0.f, 0.f};

    // prime: DMA tile 0 into buf 0
    gload_lds16(kgp + gk0, kdst0);
    gload_lds16(kgp + gk1, kdst1);
    gload_lds16(vgp + gv0, vdst0);
    gload_lds16(vgp + gv1, vdst1);

    #pragma unroll 2
    for (int it = 0; it < 32; ++it) {
        const int buf = it & 1;
        __syncthreads();   // drains vmcnt(0): DMA(it) visible; buf^1 free to overwrite
        {
            const size_t nb = (size_t)((it + 1) & 31) * 4096;  // tile base in elements
            const int bo = (buf ^ 1) * 4096;
            gload_lds16(kgp + nb + gk0, kdst0 + bo);
            gload_lds16(kgp + nb + gk1, kdst1 + bo);
            gload_lds16(vgp + nb + gv0, vdst0 + bo);
            gload_lds16(vgp + nb + gv1, vdst1 + bo);
        }
        const unsigned short* Kb = Ks + buf * 4096;
        const unsigned short* Vb = Vs + buf * 4096;

        bf16x8 vf[4];
        #pragma unroll
        for (int dt = 0; dt < 4; ++dt)
            vf[dt] = *(const bf16x8*)&Vb[vfo + dt * 512];

        #pragma unroll
        for (int kt = 0; kt < 2; ++kt) {
            bf16x8 k0 = *(const bf16x8*)&Kb[kfo[0] + kt * 1024];
            bf16x8 k1 = *(const bf16x8*)&Kb[kfo[1] + kt * 1024];
            f32x4 s[4];
            #pragma unroll
            for (int qt = 0; qt < 4; ++qt) {
                f32x4 z = (f32x4){0.f, 0.f, 0.f, 0.f};
                z = __builtin_amdgcn_mfma_f32_16x16x32_bf16(k0, qf[qt][0], z, 0, 0, 0);
                s[qt] = __builtin_amdgcn_mfma_f32_16x16x32_bf16(k1, qf[qt][1], z, 0, 0, 0);
            }
            #pragma unroll
            for (int qt = 0; qt < 4; ++qt) {
                unsigned int u[4];
                #pragma unroll
                for (int r = 0; r < 4; ++r) {
                    float p = __builtin_amdgcn_exp2f(s[qt][r]);
                    rs[qt] += p;
                    u[r] = __builtin_bit_cast(unsigned int, p);
                }
                unsigned int lo = __builtin_amdgcn_perm(u[1], u[0], 0x07060302);
                unsigned int hi = __builtin_amdgcn_perm(u[3], u[2], 0x07060302);
                unsigned long long pv = ((unsigned long long)hi << 32) | lo;
                *(unsigned long long*)&myPs[(qt * 16 + lm) * PSW9 + kt * 16 + quad * 4] = pv;
            }
        }
        // O += P V
        #pragma unroll
        for (int qt = 0; qt < 4; ++qt) {
            bf16x8 pf = *(const bf16x8*)&myPs[(qt * 16 + lm) * PSW9 + quad * 8];
            #pragma unroll
            for (int dt = 0; dt < 4; ++dt)
                o[qt][dt] = __builtin_amdgcn_mfma_f32_16x16x32_bf16(pf, vf[dt], o[qt][dt], 0, 0, 0);
        }
    }

    // quad-reduce rs
    #pragma unroll
    for (int off = 16; off < 64; off <<= 1)
        #pragma unroll
        for (int qt = 0; qt < 4; ++qt) rs[qt] += __shfl_xor(rs[qt], off, 64);

    // ---- merge the 2 k-groups (linear softmax: plain add) ----
    __syncthreads();
    float* oBuf = (float*)smem;                  // [2 qg][64 q][68], 34816 B (overlays Ks/Vs/Ps)
    float* lRed = (float*)(smem + 40960);        // [2 qg][64]
    if (kg == 1) {
        #pragma unroll
        for (int qt = 0; qt < 4; ++qt)
            #pragma unroll
            for (int dt = 0; dt < 4; ++dt)
                #pragma unroll
                for (int r = 0; r < 4; ++r)
                    oBuf[(qg * 64 + qt * 16 + quad * 4 + r) * 68 + dt * 16 + lm] = o[qt][dt][r];
        if (quad == 0) {
            #pragma unroll
            for (int qt = 0; qt < 4; ++qt) lRed[qg * 64 + qt * 16 + lm] = rs[qt];
        }
    }
    __syncthreads();
    if (kg == 0) {
        #pragma unroll
        for (int qt = 0; qt < 4; ++qt) {
            rs[qt] += lRed[qg * 64 + qt * 16 + lm];
            #pragma unroll
            for (int dt = 0; dt < 4; ++dt)
                #pragma unroll
                for (int r = 0; r < 4; ++r)
                    o[qt][dt][r] += oBuf[(qg * 64 + qt * 16 + quad * 4 + r) * 68 + dt * 16 + lm];
        }
        #pragma unroll
        for (int qt = 0; qt < 4; ++qt)
            #pragma unroll
            for (int r = 0; r < 4; ++r) {
                float inv = 1.0f / __shfl(rs[qt], quad * 4 + r, 64);
                int row = b * SEQ + q0 + qg * 64 + qt * 16 + quad * 4 + r;
                #pragma unroll
                for (int dt = 0; dt < 4; ++dt)
                    attnb[(size_t)row * HID + h * DH + dt * 16 + lm] = f2bf(o[qt][dt][r] * inv);
            }
    }
}

// ========== output GEMM: 64x128 tiles ==========
__global__ __launch_bounds__(256) void gemm_out(const unsigned short* __restrict__ A,
                                                const unsigned short* __restrict__ Bt,
                                                float* __restrict__ C)
{
    __shared__ __align__(16) unsigned short As[64 * 32];
    __shared__ __align__(16) unsigned short Bs[128 * 32];
    const int tid = threadIdx.x;
    const int w = tid >> 6, lane = tid & 63;
    const int quad = lane >> 4, lm = lane & 15;
    const int wr = (w >> 1) * 32, wc = (w & 1) * 64;
    const int bm = blockIdx.y * 64, bn = blockIdx.x * 128;
    const int m0 = tid >> 2;
    const int sk = (tid & 3) << 3;

    f32x4 acc[2][4];
    #pragma unroll
    for (int i = 0; i < 2; ++i)
        #pragma unroll
        for (int j = 0; j < 4; ++j) acc[i][j] = (f32x4){0.f, 0.f, 0.f, 0.f};

    for (int k0 = 0; k0 < 1024; k0 += 32) {
        __syncthreads();
        gload_lds16(&A [(size_t)(bm + m0     ) * 1024 + k0 + sk], As + (size_t)w * 512);
        gload_lds16(&Bt[(size_t)(bn + m0     ) * 1024 + k0 + sk], Bs + (size_t)w * 512);
        gload_lds16(&Bt[(size_t)(bn + m0 + 64) * 1024 + k0 + sk], Bs + 2048 + (size_t)w * 512);
        __syncthreads();
        bf16x8 af[2], bfr[4];
        #pragma unroll
        for (int mt = 0; mt < 2; ++mt) af[mt] = *(const bf16x8*)&As[(wr + mt * 16 + lm) * 32 + quad * 8];
        #pragma unroll
        for (int nt = 0; nt < 4; ++nt) bfr[nt] = *(const bf16x8*)&Bs[(wc + nt * 16 + lm) * 32 + quad * 8];
        #pragma unroll
        for (int mt = 0; mt < 2; ++mt)
            #pragma unroll
            for (int nt = 0; nt < 4; ++nt)
                acc[mt][nt] = __builtin_amdgcn_mfma_f32_16x16x32_bf16(af[mt], bfr[nt], acc[mt][nt], 0, 0, 0);
    }

    #pragma unroll
    for (int mt = 0; mt < 2; ++mt)
        #pragma unroll
        for (int nt = 0; nt < 4; ++nt) {
            int col = bn + wc + nt * 16 + lm;
            #pragma unroll
            for (int r = 0; r < 4; ++r) {
                int row = bm + wr + mt * 16 + quad * 4 + r;
                C[(size_t)row * 1024 + col] = acc[mt][nt][r];
            }
        }
}

extern "C" void kernel_launch(void* const* d_in, const int* in_sizes, int n_in,
                              void* d_out, int out_size, void* d_ws, size_t ws_size,
                              hipStream_t stream) {
    const float* x     = (const float*)d_in[0];
    const float* rot   = (const float*)d_in[1];
    const float* w_qkv = (const float*)d_in[2];
    const float* w_out = (const float*)d_in[3];
    float* out = (float*)d_out;

    char* ws = (char*)d_ws;
    unsigned short* xb    = (unsigned short*)(ws);                         // 8 MB
    unsigned short* qb    = (unsigned short*)(ws + (size_t)( 8u << 20));   // 8 MB [bh][seq][64]
    unsigned short* kb    = (unsigned short*)(ws + (size_t)(16u << 20));   // 8 MB [bh][seq][64]
    unsigned short* vt    = (unsigned short*)(ws + (size_t)(24u << 20));   // 8 MB [bh][seq/32][64][32]
    unsigned short* attnb = (unsigned short*)(ws + (size_t)(32u << 20));   // 8 MB
    unsigned short* wqkvT = (unsigned short*)(ws + (size_t)(40u << 20));   // 6 MB
    unsigned short* woutT = (unsigned short*)(ws + (size_t)(46u << 20));   // 2 MB
    float2*         ctab  = (float2*)        (ws + (size_t)(48u << 20));   // 1 MB

    prep<<<3584, 256, 0, stream>>>(x, rot, w_qkv, w_out, xb, ctab, wqkvT, woutT);

    gemm_qkv<<<dim3(24, 32), 256, 0, stream>>>(xb, wqkvT, ctab, qb, kb, vt);

    attn9<<<dim3(SEQ / 128, 32), 256, 0, stream>>>(qb, kb, vt, attnb);

    gemm_out<<<dim3(8, 64), 256, 0, stream>>>(attnb, woutT, out);
}